// Round 1
// baseline (273.581 us; speedup 1.0000x reference)
//
#include <hip/hip_runtime.h>
#include <hip/hip_bf16.h>
#include <hip/hip_fp16.h>

constexpr int IN_DIM = 128;
constexpr int HID    = 256;

typedef _Float16 f16x8 __attribute__((ext_vector_type(8)));
typedef float    f32x4 __attribute__((ext_vector_type(4)));

// ---------------- setup kernels ----------------

__global__ void count_deg(const int* __restrict__ dst, int* __restrict__ deg, int e) {
    int i = blockIdx.x * blockDim.x + threadIdx.x;
    if (i < e) atomicAdd(&deg[dst[i]], 1);
}

// ---- scan phase 1: per-block scan + block total; also emits dinv ----
__global__ __launch_bounds__(256) void scan_partial(const int* __restrict__ deg,
                                                    int* __restrict__ escan,
                                                    int* __restrict__ blocksum,
                                                    float* __restrict__ dinv, int n) {
    __shared__ int lds[256];
    int t = threadIdx.x;
    int i = blockIdx.x * 256 + t;
    int v = (i < n) ? deg[i] : 0;
    if (i < n) dinv[i] = rsqrtf((float)v + 1.0f);
    lds[t] = v;
    __syncthreads();
    for (int off = 1; off < 256; off <<= 1) {
        int a = lds[t];
        int w = (t >= off) ? lds[t - off] : 0;
        __syncthreads();
        lds[t] = a + w;
        __syncthreads();
    }
    if (i < n) escan[i] = lds[t] - v;
    if (t == 255) blocksum[blockIdx.x] = lds[255];
}

// ---- scan phases 2+3 fused ----
__global__ __launch_bounds__(256) void scan_rest(const int* __restrict__ escan,
                                                 const int* __restrict__ blocksum,
                                                 int nb, int* __restrict__ rowptr, int n) {
    __shared__ int lds[256];
    int t = threadIdx.x;
    int v = (t < nb) ? blocksum[t] : 0;
    lds[t] = v;
    __syncthreads();
    for (int off = 1; off < 256; off <<= 1) {
        int a = lds[t];
        int w = (t >= off) ? lds[t - off] : 0;
        __syncthreads();
        lds[t] = a + w;
        __syncthreads();
    }
    int boff = (blockIdx.x > 0) ? lds[blockIdx.x - 1] : 0;
    int i = blockIdx.x * 256 + t;
    if (i < n) rowptr[i] = escan[i] + boff;
    if (blockIdx.x == 0 && t == 0) rowptr[n] = lds[nb - 1];
}

// Single packed (src, weight) int2 write instead of two scattered 4B writes.
__global__ void scatter_edges(const int* __restrict__ src, const int* __restrict__ dst,
                              const int* __restrict__ rowptr, int* __restrict__ cursor,
                              const float* __restrict__ dinv,
                              int2* __restrict__ esw, int e) {
    int i = blockIdx.x * blockDim.x + threadIdx.x;
    if (i < e) {
        int d = dst[i];
        int s = src[i];
        int p = atomicAdd(&cursor[d], 1);
        esw[rowptr[d] + p] = make_int2(s, __float_as_int(dinv[s] * dinv[d]));
    }
}

// ---- fused: W1/W2 -> fp16 panels, x -> fp16, zero deg+cursor ----
__device__ inline void conv_B_elem(const float* B, ushort* Bp, int id) {
    int k  = id >> 6;
    int n4 = (id & 63) * 4;
    float4 v = *(const float4*)(B + (size_t)k * 256 + n4);
    size_t base = (size_t)(k >> 5) * (256 * 32) + (k & 31);
    Bp[base + (size_t)(n4 + 0) * 32] = __half_as_ushort(__float2half(v.x));
    Bp[base + (size_t)(n4 + 1) * 32] = __half_as_ushort(__float2half(v.y));
    Bp[base + (size_t)(n4 + 2) * 32] = __half_as_ushort(__float2half(v.z));
    Bp[base + (size_t)(n4 + 3) * 32] = __half_as_ushort(__float2half(v.w));
}

__global__ void convert_inputs(const float* __restrict__ W1, ushort* __restrict__ B1p,
                               const float* __restrict__ W2, ushort* __restrict__ B2p,
                               const float* __restrict__ x, ushort* __restrict__ xh,
                               int total4, int* __restrict__ deg,
                               int* __restrict__ cursor, int n) {
    int id = blockIdx.x * 256 + threadIdx.x;
    constexpr int C1 = IN_DIM * 64;
    constexpr int C2 = C1 + HID * 64;
    if (id < C1) {
        conv_B_elem(W1, B1p, id);
    } else if (id < C2) {
        conv_B_elem(W2, B2p, id - C1);
    } else if (id < C2 + total4) {
        int i = id - C2;
        float4 v = *(const float4*)(x + (size_t)i * 4);
        ushort4 o;
        o.x = __half_as_ushort(__float2half(v.x));
        o.y = __half_as_ushort(__float2half(v.y));
        o.z = __half_as_ushort(__float2half(v.z));
        o.w = __half_as_ushort(__float2half(v.w));
        *(ushort4*)(xh + (size_t)i * 4) = o;
    } else {
        int i = id - (C2 + total4);
        if (i < n) { deg[i] = 0; cursor[i] = 0; }
    }
}

// ---------------- fused aggregate + MFMA GEMM ----------------
// Each block owns 32 output rows. Wave w aggregates rows w*8..w*8+7 with the
// 8-deep shfl-gather loop, writing fp16 results DIRECTLY into the Asm LDS
// tile in the [chunk][row][32] layout the MFMA fragments read. This removes
// the A-panel HBM round trip (write 12.8/25.6 MB + read 12.8/25.6 MB) that
// the separate aggregate_p -> gemm_f16 pipeline paid.
// MODE 1: C16[M,256] = fp16(relu(agg@B + bias))
// MODE 2: out[M,2]  = relu(agg@B + bias) @ Wl + bl
template <int K, int MODE>
__global__ __launch_bounds__(256, 3) void fused_layer(const ushort* __restrict__ h,
                                                      const int* __restrict__ rowptr,
                                                      const int2* __restrict__ esw,
                                                      const float* __restrict__ dinv,
                                                      const ushort* __restrict__ Bp,
                                                      const float* __restrict__ bias,
                                                      ushort* __restrict__ C16,
                                                      const float* __restrict__ Wl,
                                                      const float* __restrict__ bl,
                                                      float* __restrict__ out,
                                                      int M) {
    constexpr int NC = K / 32;   // 4 or 8 chunks of 32 k
    constexpr int VH = K / 64;   // halves per lane: 2 or 4
    __shared__ ushort Asm[NC * 1024];   // A tile [chunk][row 0..31][32]
    __shared__ ushort Bsm[2][8192];     // B chunk dbuf (16 KB each)

    int tid  = threadIdx.x;
    int w    = tid >> 6;
    int lane = tid & 63;
    int l15  = lane & 15;
    int quad = lane >> 4;
    int row0 = blockIdx.x * 32;

    // B chunk-0 prefetch: async DMA completes under the aggregation phase;
    // the first __syncthreads (full vmcnt drain) doubles as its arrival wait.
#pragma unroll
    for (int j = 0; j < 4; j++) {
        int seg = w * 4 + j;
        const ushort* g = Bp + (size_t)seg * 512;
        ushort* l = Bsm[0] + seg * 512;
        __builtin_amdgcn_global_load_lds(
            (const __attribute__((address_space(1))) uint*)(g + (size_t)lane * 8),
            (__attribute__((address_space(3))) uint*)l, 16, 0, 0);
    }

    // ---- aggregation: wave w handles tile rows w*8 .. w*8+7 ----
    for (int rr = 0; rr < 8; rr++) {
        int r    = w * 8 + rr;
        int node = row0 + r;
        float av[VH];
#pragma unroll
        for (int v = 0; v < VH; v++) av[v] = 0.f;
        if (node < M) {
            float di = dinv[node];
            float sw = di * di;
            const ushort* rowp = h + (size_t)node * K + lane * VH;
            if constexpr (VH == 4) {
                uint2 u = *(const uint2*)rowp;
                float2 fa = __half22float2(*(__half2*)&u.x);
                float2 fb = __half22float2(*(__half2*)&u.y);
                av[0] = fa.x * sw; av[1] = fa.y * sw; av[2] = fb.x * sw; av[3] = fb.y * sw;
            } else {
                uint u = *(const uint*)rowp;
                float2 fa = __half22float2(*(__half2*)&u);
                av[0] = fa.x * sw; av[1] = fa.y * sw;
            }
            int beg = rowptr[node], fin = rowptr[node + 1];
            for (int b = beg; b < fin; b += 64) {
                int cnt = fin - b;
                if (cnt > 64) cnt = 64;
                int2 pk = (lane < cnt) ? esw[b + lane] : make_int2(0, 0);
                int   sv = pk.x;
                float wv = __int_as_float(pk.y);
                int t = 0;
                for (; t + 8 <= cnt; t += 8) {
                    float wr[8];
                    if constexpr (VH == 4) {
                        uint2 u[8];
#pragma unroll
                        for (int k = 0; k < 8; k++) {
                            int s = __shfl(sv, t + k);
                            wr[k] = __shfl(wv, t + k);
                            u[k] = *(const uint2*)(h + (size_t)s * K + lane * VH);
                        }
#pragma unroll
                        for (int k = 0; k < 8; k++) {
                            float2 fa = __half22float2(*(__half2*)&u[k].x);
                            float2 fb = __half22float2(*(__half2*)&u[k].y);
                            av[0] += fa.x * wr[k]; av[1] += fa.y * wr[k];
                            av[2] += fb.x * wr[k]; av[3] += fb.y * wr[k];
                        }
                    } else {
                        uint u[8];
#pragma unroll
                        for (int k = 0; k < 8; k++) {
                            int s = __shfl(sv, t + k);
                            wr[k] = __shfl(wv, t + k);
                            u[k] = *(const uint*)(h + (size_t)s * K + lane * VH);
                        }
#pragma unroll
                        for (int k = 0; k < 8; k++) {
                            float2 fa = __half22float2(*(__half2*)&u[k]);
                            av[0] += fa.x * wr[k]; av[1] += fa.y * wr[k];
                        }
                    }
                }
                for (; t + 4 <= cnt; t += 4) {
                    float wr[4];
                    if constexpr (VH == 4) {
                        uint2 u[4];
#pragma unroll
                        for (int k = 0; k < 4; k++) {
                            int s = __shfl(sv, t + k);
                            wr[k] = __shfl(wv, t + k);
                            u[k] = *(const uint2*)(h + (size_t)s * K + lane * VH);
                        }
#pragma unroll
                        for (int k = 0; k < 4; k++) {
                            float2 fa = __half22float2(*(__half2*)&u[k].x);
                            float2 fb = __half22float2(*(__half2*)&u[k].y);
                            av[0] += fa.x * wr[k]; av[1] += fa.y * wr[k];
                            av[2] += fb.x * wr[k]; av[3] += fb.y * wr[k];
                        }
                    } else {
                        uint u[4];
#pragma unroll
                        for (int k = 0; k < 4; k++) {
                            int s = __shfl(sv, t + k);
                            wr[k] = __shfl(wv, t + k);
                            u[k] = *(const uint*)(h + (size_t)s * K + lane * VH);
                        }
#pragma unroll
                        for (int k = 0; k < 4; k++) {
                            float2 fa = __half22float2(*(__half2*)&u[k]);
                            av[0] += fa.x * wr[k]; av[1] += fa.y * wr[k];
                        }
                    }
                }
                for (; t < cnt; t++) {
                    int   s = __shfl(sv, t);
                    float wt = __shfl(wv, t);
                    const ushort* rp = h + (size_t)s * K + lane * VH;
                    if constexpr (VH == 4) {
                        uint2 u = *(const uint2*)rp;
                        float2 fa = __half22float2(*(__half2*)&u.x);
                        float2 fb = __half22float2(*(__half2*)&u.y);
                        av[0] += fa.x * wt; av[1] += fa.y * wt;
                        av[2] += fb.x * wt; av[3] += fb.y * wt;
                    } else {
                        uint u = *(const uint*)rp;
                        float2 fa = __half22float2(*(__half2*)&u);
                        av[0] += fa.x * wt; av[1] += fa.y * wt;
                    }
                }
            }
        }
        // store row r into Asm: channel ch = lane*VH+j -> [ch>>5][r][ch&31]
        if constexpr (VH == 4) {
            __half2 p0 = __floats2half2_rn(av[0], av[1]);
            __half2 p1 = __floats2half2_rn(av[2], av[3]);
            int c = lane >> 3;
            int inner = (lane & 7) * 4;
            *(uint2*)&Asm[c * 1024 + r * 32 + inner] = make_uint2(*(uint*)&p0, *(uint*)&p1);
        } else {
            __half2 p0 = __floats2half2_rn(av[0], av[1]);
            int c = lane >> 4;
            int inner = (lane & 15) * 2;
            *(uint*)&Asm[c * 1024 + r * 32 + inner] = *(uint*)&p0;
        }
    }

    // ---- MFMA GEMM over the LDS A tile, B double-buffered via LDS-DMA ----
    f32x4 acc[2][4] = {};
#pragma unroll
    for (int c = 0; c < NC; c++) {
        __syncthreads();   // c=0: Asm writes visible + B[0] DMA drained
        if (c + 1 < NC) {
            int nb_ = (c + 1) & 1;
#pragma unroll
            for (int j = 0; j < 4; j++) {
                int seg = w * 4 + j;
                const ushort* g = Bp + (size_t)(c + 1) * 8192 + (size_t)seg * 512;
                ushort* l = Bsm[nb_] + seg * 512;
                __builtin_amdgcn_global_load_lds(
                    (const __attribute__((address_space(1))) uint*)(g + (size_t)lane * 8),
                    (__attribute__((address_space(3))) uint*)l, 16, 0, 0);
            }
        }
        f16x8 fa[2], fb[4];
#pragma unroll
        for (int i = 0; i < 2; i++) {
            int off = c * 1024 + (i * 16 + l15) * 32 + quad * 8;
            fa[i] = *(const f16x8*)&Asm[off];
        }
#pragma unroll
        for (int j = 0; j < 4; j++) {
            int off = (w * 64 + j * 16 + l15) * 32 + quad * 8;
            fb[j] = *(const f16x8*)&Bsm[c & 1][off];
        }
#pragma unroll
        for (int i = 0; i < 2; i++)
#pragma unroll
            for (int j = 0; j < 4; j++)
                acc[i][j] = __builtin_amdgcn_mfma_f32_16x16x32_f16(fa[i], fb[j], acc[i][j], 0, 0, 0);
    }

    float bj[4];
#pragma unroll
    for (int j = 0; j < 4; j++) bj[j] = bias[w * 64 + j * 16 + l15];

    if constexpr (MODE == 1) {
#pragma unroll
        for (int i = 0; i < 2; i++)
#pragma unroll
            for (int reg = 0; reg < 4; reg++) {
                int r = row0 + i * 16 + quad * 4 + reg;
                if (r < M) {
                    ushort* cp = C16 + (size_t)r * 256 + w * 64 + l15;
#pragma unroll
                    for (int j = 0; j < 4; j++) {
                        float v = fmaxf(acc[i][j][reg] + bj[j], 0.f);
                        cp[j * 16] = __half_as_ushort(__float2half(v));
                    }
                }
            }
    } else {
        // overlay the cross-wave partial buffer on Asm (done with A reads);
        // barrier first so no wave is still reading its last A fragments.
        __syncthreads();
        float (*part)[32][2] = (float (*)[32][2])Asm;
        float wl0[4], wl1[4];
#pragma unroll
        for (int j = 0; j < 4; j++) {
            int cj = w * 64 + j * 16 + l15;
            float2 wv = *(const float2*)(Wl + cj * 2);
            wl0[j] = wv.x; wl1[j] = wv.y;
        }
#pragma unroll
        for (int i = 0; i < 2; i++)
#pragma unroll
            for (int reg = 0; reg < 4; reg++) {
                float s0 = 0.f, s1 = 0.f;
#pragma unroll
                for (int j = 0; j < 4; j++) {
                    float v = fmaxf(acc[i][j][reg] + bj[j], 0.f);
                    s0 += v * wl0[j];
                    s1 += v * wl1[j];
                }
#pragma unroll
                for (int off = 1; off < 16; off <<= 1) {
                    s0 += __shfl_xor(s0, off);
                    s1 += __shfl_xor(s1, off);
                }
                if (l15 == 0) {
                    int r = i * 16 + quad * 4 + reg;
                    part[w][r][0] = s0;
                    part[w][r][1] = s1;
                }
            }
        __syncthreads();
        if (tid < 64) {
            int r = tid >> 1, o = tid & 1;
            int grr = row0 + r;
            if (grr < M) {
                float s = part[0][r][o] + part[1][r][o] + part[2][r][o] + part[3][r][o] + bl[o];
                out[(size_t)grr * 2 + o] = s;
            }
        }
    }
}

// ---------------- launch ----------------

extern "C" void kernel_launch(void* const* d_in, const int* in_sizes, int n_in,
                              void* d_out, int out_size, void* d_ws, size_t ws_size,
                              hipStream_t stream) {
    const float* x  = (const float*)d_in[0];
    const int*   ei = (const int*)d_in[1];
    const float* W1 = (const float*)d_in[2];
    const float* b1 = (const float*)d_in[3];
    const float* W2 = (const float*)d_in[4];
    const float* b2 = (const float*)d_in[5];
    const float* Wl = (const float*)d_in[6];
    const float* bl = (const float*)d_in[7];
    float* out = (float*)d_out;

    int n = in_sizes[0] / IN_DIM;  // 50000
    int e = in_sizes[1] / 2;       // 600000
    const int* src = ei;
    const int* dst = ei + e;

    int gblocks = (n + 31) / 32;   // BM=32

    char* ws = (char*)d_ws;
    size_t off = 0;
    auto alloc = [&](size_t bytes) -> void* {
        void* p = ws + off;
        off += (bytes + 255) & ~(size_t)255;
        return p;
    };
    int*    deg    = (int*)alloc((size_t)n * 4);
    int*    cursor = (int*)alloc((size_t)n * 4);
    float*  dinv   = (float*)alloc((size_t)n * 4);
    int*    rowptr = (int*)alloc((size_t)(n + 1) * 4);
    int*    escan  = (int*)alloc((size_t)n * 4);
    int*    bsum   = (int*)alloc(256 * 4);
    int2*   esw    = (int2*)alloc((size_t)e * 8);
    ushort* xh     = (ushort*)alloc((size_t)n * IN_DIM * 2);
    ushort* h1     = (ushort*)alloc((size_t)n * HID * 2);
    ushort* B1p    = (ushort*)alloc((size_t)IN_DIM * 256 * 2);
    ushort* B2p    = (ushort*)alloc((size_t)HID * 256 * 2);

    int nb = (n + 255) / 256;   // 196 (<= 256 required by scan_rest)
    int eb = (e + 255) / 256;

    int total4 = n * IN_DIM / 4;
    int citems = IN_DIM * 64 + HID * 64 + total4 + n;
    convert_inputs<<<(citems + 255) / 256, 256, 0, stream>>>(W1, B1p, W2, B2p, x, xh,
                                                             total4, deg, cursor, n);

    count_deg<<<eb, 256, 0, stream>>>(dst, deg, e);
    scan_partial<<<nb, 256, 0, stream>>>(deg, escan, bsum, dinv, n);
    scan_rest<<<nb, 256, 0, stream>>>(escan, bsum, nb, rowptr, n);
    scatter_edges<<<eb, 256, 0, stream>>>(src, dst, rowptr, cursor, dinv, esw, e);

    // layer 1: fused aggregate(xh) + GEMM(W1) -> fp16 h1
    fused_layer<IN_DIM, 1><<<gblocks, 256, 0, stream>>>(xh, rowptr, esw, dinv, B1p,
                                                        b1, h1, nullptr, nullptr,
                                                        nullptr, n);

    // layer 2: fused aggregate(h1) + GEMM(W2) + final projection
    fused_layer<HID, 2><<<gblocks, 256, 0, stream>>>(h1, rowptr, esw, dinv, B2p,
                                                     b2, nullptr, Wl, bl, out, n);
}

// Round 2
// 268.217 us; speedup vs baseline: 1.0200x; 1.0200x over previous
//
#include <hip/hip_runtime.h>
#include <hip/hip_bf16.h>
#include <hip/hip_fp16.h>

constexpr int IN_DIM = 128;
constexpr int HID    = 256;

typedef _Float16 f16x8 __attribute__((ext_vector_type(8)));
typedef float    f32x4 __attribute__((ext_vector_type(4)));

// ---------------- setup kernels ----------------

__global__ void count_deg(const int* __restrict__ dst, int* __restrict__ deg, int e) {
    int i = blockIdx.x * blockDim.x + threadIdx.x;
    if (i < e) atomicAdd(&deg[dst[i]], 1);
}

// ---- scan phase 1: per-block scan + block total; also emits dinv ----
__global__ __launch_bounds__(256) void scan_partial(const int* __restrict__ deg,
                                                    int* __restrict__ escan,
                                                    int* __restrict__ blocksum,
                                                    float* __restrict__ dinv, int n) {
    __shared__ int lds[256];
    int t = threadIdx.x;
    int i = blockIdx.x * 256 + t;
    int v = (i < n) ? deg[i] : 0;
    if (i < n) dinv[i] = rsqrtf((float)v + 1.0f);
    lds[t] = v;
    __syncthreads();
    for (int off = 1; off < 256; off <<= 1) {
        int a = lds[t];
        int w = (t >= off) ? lds[t - off] : 0;
        __syncthreads();
        lds[t] = a + w;
        __syncthreads();
    }
    if (i < n) escan[i] = lds[t] - v;
    if (t == 255) blocksum[blockIdx.x] = lds[255];
}

// ---- scan phases 2+3 fused ----
__global__ __launch_bounds__(256) void scan_rest(const int* __restrict__ escan,
                                                 const int* __restrict__ blocksum,
                                                 int nb, int* __restrict__ rowptr, int n) {
    __shared__ int lds[256];
    int t = threadIdx.x;
    int v = (t < nb) ? blocksum[t] : 0;
    lds[t] = v;
    __syncthreads();
    for (int off = 1; off < 256; off <<= 1) {
        int a = lds[t];
        int w = (t >= off) ? lds[t - off] : 0;
        __syncthreads();
        lds[t] = a + w;
        __syncthreads();
    }
    int boff = (blockIdx.x > 0) ? lds[blockIdx.x - 1] : 0;
    int i = blockIdx.x * 256 + t;
    if (i < n) rowptr[i] = escan[i] + boff;
    if (blockIdx.x == 0 && t == 0) rowptr[n] = lds[nb - 1];
}

// Single packed (src, weight) int2 write instead of two scattered 4B writes.
__global__ void scatter_edges(const int* __restrict__ src, const int* __restrict__ dst,
                              const int* __restrict__ rowptr, int* __restrict__ cursor,
                              const float* __restrict__ dinv,
                              int2* __restrict__ esw, int e) {
    int i = blockIdx.x * blockDim.x + threadIdx.x;
    if (i < e) {
        int d = dst[i];
        int s = src[i];
        int p = atomicAdd(&cursor[d], 1);
        esw[rowptr[d] + p] = make_int2(s, __float_as_int(dinv[s] * dinv[d]));
    }
}

// ---- fused: W1/W2 -> fp16 panels, x -> fp16, zero deg+cursor ----
__device__ inline void conv_B_elem(const float* B, ushort* Bp, int id) {
    int k  = id >> 6;
    int n4 = (id & 63) * 4;
    float4 v = *(const float4*)(B + (size_t)k * 256 + n4);
    size_t base = (size_t)(k >> 5) * (256 * 32) + (k & 31);
    Bp[base + (size_t)(n4 + 0) * 32] = __half_as_ushort(__float2half(v.x));
    Bp[base + (size_t)(n4 + 1) * 32] = __half_as_ushort(__float2half(v.y));
    Bp[base + (size_t)(n4 + 2) * 32] = __half_as_ushort(__float2half(v.z));
    Bp[base + (size_t)(n4 + 3) * 32] = __half_as_ushort(__float2half(v.w));
}

__global__ void convert_inputs(const float* __restrict__ W1, ushort* __restrict__ B1p,
                               const float* __restrict__ W2, ushort* __restrict__ B2p,
                               const float* __restrict__ x, ushort* __restrict__ xh,
                               int total4, int* __restrict__ deg,
                               int* __restrict__ cursor, int n) {
    int id = blockIdx.x * 256 + threadIdx.x;
    constexpr int C1 = IN_DIM * 64;
    constexpr int C2 = C1 + HID * 64;
    if (id < C1) {
        conv_B_elem(W1, B1p, id);
    } else if (id < C2) {
        conv_B_elem(W2, B2p, id - C1);
    } else if (id < C2 + total4) {
        int i = id - C2;
        float4 v = *(const float4*)(x + (size_t)i * 4);
        ushort4 o;
        o.x = __half_as_ushort(__float2half(v.x));
        o.y = __half_as_ushort(__float2half(v.y));
        o.z = __half_as_ushort(__float2half(v.z));
        o.w = __half_as_ushort(__float2half(v.w));
        *(ushort4*)(xh + (size_t)i * 4) = o;
    } else {
        int i = id - (C2 + total4);
        if (i < n) { deg[i] = 0; cursor[i] = 0; }
    }
}

// ---------------- aggregation: wide gather (16B/lane, row-group split) ------
// One wave per node. Lanes split into row-groups: for K=256 two groups of 32
// lanes each cover one full 512B row with uint4 loads -> each gather instr
// fetches 2 rows (1KB in flight per instr, 2x the old uint2 scheme); for
// K=128 four groups of 16 lanes -> 4 rows/instr. Per-group partial channel
// accumulators are combined with 1-2 shfl_xor at the end. Halves the
// shfl/issue count per edge and doubles/quadruples outstanding bytes.
template <int K>  // 128 or 256
__global__ __launch_bounds__(256, 8) void aggregate_w(const ushort* __restrict__ h,
                                                      const int* __restrict__ rowptr,
                                                      const int2* __restrict__ esw,
                                                      const float* __restrict__ dinv,
                                                      ushort* __restrict__ Pp,
                                                      int n, int Mp) {
    constexpr int LPR = K / 8;              // lanes per row (16B = 8 halves each)
    constexpr int R   = 64 / LPR;           // rows gathered per instruction (2 or 4)
    constexpr int D   = (K == 256) ? 6 : 4; // load depth (R*D edges per batch)

    int wid  = (blockIdx.x * 256 + threadIdx.x) >> 6;
    int lane = threadIdx.x & 63;
    if (wid >= n) return;
    int g = lane / LPR;   // row-group id
    int p = lane % LPR;   // 16B slot within row -> channels p*8 .. p*8+7

    float acc[8];
#pragma unroll
    for (int i = 0; i < 8; i++) acc[i] = 0.f;

    float di = dinv[wid];
    if (g == 0) {  // self-loop term, group 0 only (others would duplicate)
        float sw = di * di;
        uint4 u = *(const uint4*)(h + (size_t)wid * K + p * 8);
        float2 f0 = __half22float2(*(__half2*)&u.x);
        float2 f1 = __half22float2(*(__half2*)&u.y);
        float2 f2 = __half22float2(*(__half2*)&u.z);
        float2 f3 = __half22float2(*(__half2*)&u.w);
        acc[0] = f0.x * sw; acc[1] = f0.y * sw;
        acc[2] = f1.x * sw; acc[3] = f1.y * sw;
        acc[4] = f2.x * sw; acc[5] = f2.y * sw;
        acc[6] = f3.x * sw; acc[7] = f3.y * sw;
    }

    int beg = rowptr[wid], fin = rowptr[wid + 1];
    for (int b = beg; b < fin; b += 64) {
        int cnt = fin - b;
        if (cnt > 64) cnt = 64;
        int2 pk = (lane < cnt) ? esw[b + lane] : make_int2(0, 0);
        int   sv = pk.x;
        float wv = __int_as_float(pk.y);
        for (int t = 0; t < cnt; t += R * D) {
            uint4 u[D];
            float wr[D];
#pragma unroll
            for (int k = 0; k < D; k++) {
                int e  = t + k * R + g;       // edge handled by this lane's group
                int ee = (e < cnt) ? e : 0;   // clamp (lane 0 always valid: cnt>=1)
                int s   = __shfl(sv, ee);
                float w = __shfl(wv, ee);
                wr[k] = (e < cnt) ? w : 0.f;
                u[k]  = *(const uint4*)(h + (size_t)s * K + p * 8);
            }
#pragma unroll
            for (int k = 0; k < D; k++) {
                float2 f0 = __half22float2(*(__half2*)&u[k].x);
                float2 f1 = __half22float2(*(__half2*)&u[k].y);
                float2 f2 = __half22float2(*(__half2*)&u[k].z);
                float2 f3 = __half22float2(*(__half2*)&u[k].w);
                acc[0] += f0.x * wr[k]; acc[1] += f0.y * wr[k];
                acc[2] += f1.x * wr[k]; acc[3] += f1.y * wr[k];
                acc[4] += f2.x * wr[k]; acc[5] += f2.y * wr[k];
                acc[6] += f3.x * wr[k]; acc[7] += f3.y * wr[k];
            }
        }
    }

    // combine row-group partials (channels identical across groups)
#pragma unroll
    for (int i = 0; i < 8; i++) {
        if constexpr (R == 4) acc[i] += __shfl_xor(acc[i], 16);
        acc[i] += __shfl_xor(acc[i], 32);
    }

    if (g == 0) {
        __half2 q0 = __floats2half2_rn(acc[0], acc[1]);
        __half2 q1 = __floats2half2_rn(acc[2], acc[3]);
        __half2 q2 = __floats2half2_rn(acc[4], acc[5]);
        __half2 q3 = __floats2half2_rn(acc[6], acc[7]);
        int chunk = p >> 2;          // (p*8) / 32
        int inner = (p & 3) * 8;     // (p*8) % 32
        uint4 o;
        o.x = *(uint*)&q0; o.y = *(uint*)&q1; o.z = *(uint*)&q2; o.w = *(uint*)&q3;
        *(uint4*)(Pp + (size_t)chunk * Mp * 32 + (size_t)wid * 32 + inner) = o;
    }
}

// ---------------- fp16 MFMA GEMM: A + B both via LDS-DMA (m97-style) -------
// MODE 1: C16[M,256] = fp16(relu(A@B + bias))
// MODE 2: out[M,2]  = relu(A@B + bias) @ Wl + bl
template <int K, int MODE>
__global__ __launch_bounds__(256, 3) void gemm_f16(const ushort* __restrict__ Ap,
                                                   const ushort* __restrict__ Bp,
                                                   const float* __restrict__ bias,
                                                   ushort* __restrict__ C16,
                                                   const float* __restrict__ Wl,
                                                   const float* __restrict__ bl,
                                                   float* __restrict__ out,
                                                   int M, int Mp) {
    constexpr int NC = K / 32;
    __shared__ ushort Asm[NC * 1024];   // A tile [chunk][row 0..31][32]
    __shared__ ushort Bsm[2][8192];     // B chunk dbuf (16 KB each)
    __shared__ float part[4][32][2];    // MODE 2 only

    int tid  = threadIdx.x;
    int w    = tid >> 6;
    int lane = tid & 63;
    int l15  = lane & 15;
    int quad = lane >> 4;
    int row0 = blockIdx.x * 32;

    constexpr int TOTA = NC * 2;
    for (int j = w; j < TOTA; j += 4) {
        int c   = j >> 1;
        int sub = j & 1;
        const ushort* g = Ap + (size_t)c * Mp * 32 + (size_t)(row0 + sub * 16) * 32;
        ushort* l = Asm + c * 1024 + sub * 512;
        __builtin_amdgcn_global_load_lds(
            (const __attribute__((address_space(1))) uint*)(g + (size_t)lane * 8),
            (__attribute__((address_space(3))) uint*)l, 16, 0, 0);
    }
#pragma unroll
    for (int j = 0; j < 4; j++) {
        int seg = w * 4 + j;
        const ushort* g = Bp + (size_t)seg * 512;
        ushort* l = Bsm[0] + seg * 512;
        __builtin_amdgcn_global_load_lds(
            (const __attribute__((address_space(1))) uint*)(g + (size_t)lane * 8),
            (__attribute__((address_space(3))) uint*)l, 16, 0, 0);
    }

    f32x4 acc[2][4] = {};
#pragma unroll
    for (int c = 0; c < NC; c++) {
        __syncthreads();
        if (c + 1 < NC) {
            int nb_ = (c + 1) & 1;
#pragma unroll
            for (int j = 0; j < 4; j++) {
                int seg = w * 4 + j;
                const ushort* g = Bp + (size_t)(c + 1) * 8192 + (size_t)seg * 512;
                ushort* l = Bsm[nb_] + seg * 512;
                __builtin_amdgcn_global_load_lds(
                    (const __attribute__((address_space(1))) uint*)(g + (size_t)lane * 8),
                    (__attribute__((address_space(3))) uint*)l, 16, 0, 0);
            }
        }
        f16x8 fa[2], fb[4];
#pragma unroll
        for (int i = 0; i < 2; i++) {
            int off = c * 1024 + (i * 16 + l15) * 32 + quad * 8;
            fa[i] = *(const f16x8*)&Asm[off];
        }
#pragma unroll
        for (int j = 0; j < 4; j++) {
            int off = (w * 64 + j * 16 + l15) * 32 + quad * 8;
            fb[j] = *(const f16x8*)&Bsm[c & 1][off];
        }
#pragma unroll
        for (int i = 0; i < 2; i++)
#pragma unroll
            for (int j = 0; j < 4; j++)
                acc[i][j] = __builtin_amdgcn_mfma_f32_16x16x32_f16(fa[i], fb[j], acc[i][j], 0, 0, 0);
    }

    float bj[4];
#pragma unroll
    for (int j = 0; j < 4; j++) bj[j] = bias[w * 64 + j * 16 + l15];

    if constexpr (MODE == 1) {
#pragma unroll
        for (int i = 0; i < 2; i++)
#pragma unroll
            for (int reg = 0; reg < 4; reg++) {
                int r = row0 + i * 16 + quad * 4 + reg;
                if (r < M) {
                    ushort* cp = C16 + (size_t)r * 256 + w * 64 + l15;
#pragma unroll
                    for (int j = 0; j < 4; j++) {
                        float v = fmaxf(acc[i][j][reg] + bj[j], 0.f);
                        cp[j * 16] = __half_as_ushort(__float2half(v));
                    }
                }
            }
    } else {
        float wl0[4], wl1[4];
#pragma unroll
        for (int j = 0; j < 4; j++) {
            int cj = w * 64 + j * 16 + l15;
            float2 wv = *(const float2*)(Wl + cj * 2);
            wl0[j] = wv.x; wl1[j] = wv.y;
        }
#pragma unroll
        for (int i = 0; i < 2; i++)
#pragma unroll
            for (int reg = 0; reg < 4; reg++) {
                float s0 = 0.f, s1 = 0.f;
#pragma unroll
                for (int j = 0; j < 4; j++) {
                    float v = fmaxf(acc[i][j][reg] + bj[j], 0.f);
                    s0 += v * wl0[j];
                    s1 += v * wl1[j];
                }
#pragma unroll
                for (int off = 1; off < 16; off <<= 1) {
                    s0 += __shfl_xor(s0, off);
                    s1 += __shfl_xor(s1, off);
                }
                if (l15 == 0) {
                    int r = i * 16 + quad * 4 + reg;
                    part[w][r][0] = s0;
                    part[w][r][1] = s1;
                }
            }
        __syncthreads();
        if (tid < 64) {
            int r = tid >> 1, o = tid & 1;
            int grr = row0 + r;
            if (grr < M) {
                float s = part[0][r][o] + part[1][r][o] + part[2][r][o] + part[3][r][o] + bl[o];
                out[(size_t)grr * 2 + o] = s;
            }
        }
    }
}

// ---------------- launch ----------------

extern "C" void kernel_launch(void* const* d_in, const int* in_sizes, int n_in,
                              void* d_out, int out_size, void* d_ws, size_t ws_size,
                              hipStream_t stream) {
    const float* x  = (const float*)d_in[0];
    const int*   ei = (const int*)d_in[1];
    const float* W1 = (const float*)d_in[2];
    const float* b1 = (const float*)d_in[3];
    const float* W2 = (const float*)d_in[4];
    const float* b2 = (const float*)d_in[5];
    const float* Wl = (const float*)d_in[6];
    const float* bl = (const float*)d_in[7];
    float* out = (float*)d_out;

    int n = in_sizes[0] / IN_DIM;  // 50000
    int e = in_sizes[1] / 2;       // 600000
    const int* src = ei;
    const int* dst = ei + e;

    int gblocks = (n + 31) / 32;   // BM=32
    int Mp = gblocks * 32;

    char* ws = (char*)d_ws;
    size_t off = 0;
    auto alloc = [&](size_t bytes) -> void* {
        void* p = ws + off;
        off += (bytes + 255) & ~(size_t)255;
        return p;
    };
    int*    deg    = (int*)alloc((size_t)n * 4);
    int*    cursor = (int*)alloc((size_t)n * 4);
    float*  dinv   = (float*)alloc((size_t)n * 4);
    int*    rowptr = (int*)alloc((size_t)(n + 1) * 4);
    int*    escan  = (int*)alloc((size_t)n * 4);
    int*    bsum   = (int*)alloc(256 * 4);
    int2*   esw    = (int2*)alloc((size_t)e * 8);
    ushort* xh     = (ushort*)alloc((size_t)n * IN_DIM * 2);
    ushort* h1     = (ushort*)alloc((size_t)n * HID * 2);
    ushort* A1p    = (ushort*)alloc((size_t)Mp * IN_DIM * 2);
    ushort* A2p    = (ushort*)alloc((size_t)Mp * HID * 2);
    ushort* B1p    = (ushort*)alloc((size_t)IN_DIM * 256 * 2);
    ushort* B2p    = (ushort*)alloc((size_t)HID * 256 * 2);

    int nb = (n + 255) / 256;   // 196 (<= 256 required by scan_rest)
    int eb = (e + 255) / 256;

    int total4 = n * IN_DIM / 4;
    int citems = IN_DIM * 64 + HID * 64 + total4 + n;
    convert_inputs<<<(citems + 255) / 256, 256, 0, stream>>>(W1, B1p, W2, B2p, x, xh,
                                                             total4, deg, cursor, n);

    count_deg<<<eb, 256, 0, stream>>>(dst, deg, e);
    scan_partial<<<nb, 256, 0, stream>>>(deg, escan, bsum, dinv, n);
    scan_rest<<<nb, 256, 0, stream>>>(escan, bsum, nb, rowptr, n);
    scatter_edges<<<eb, 256, 0, stream>>>(src, dst, rowptr, cursor, dinv, esw, e);

    // layer 1: wide-gather aggregate fp16 x -> A1 panel, MFMA GEMM -> fp16 h1
    aggregate_w<IN_DIM><<<(n + 3) / 4, 256, 0, stream>>>(xh, rowptr, esw, dinv,
                                                         A1p, n, Mp);
    gemm_f16<IN_DIM, 1><<<gblocks, 256, 0, stream>>>(A1p, B1p, b1, h1,
                                                     nullptr, nullptr, nullptr, n, Mp);

    // layer 2: wide-gather aggregate fp16 h1 -> A2 panel, GEMM + final proj
    aggregate_w<HID><<<(n + 3) / 4, 256, 0, stream>>>(h1, rowptr, esw, dinv,
                                                      A2p, n, Mp);
    gemm_f16<HID, 2><<<gblocks, 256, 0, stream>>>(A2p, B2p, b2, nullptr,
                                                  Wl, bl, out, n, Mp);
}

// Round 3
// 235.059 us; speedup vs baseline: 1.1639x; 1.1411x over previous
//
#include <hip/hip_runtime.h>
#include <hip/hip_bf16.h>
#include <hip/hip_fp16.h>

constexpr int IN_DIM = 128;
constexpr int HID    = 256;

typedef _Float16 f16x8 __attribute__((ext_vector_type(8)));
typedef float    f32x4 __attribute__((ext_vector_type(4)));

// ---------------- setup kernels ----------------

__global__ void zero_deg(int* __restrict__ deg, int n) {
    int i = blockIdx.x * blockDim.x + threadIdx.x;
    if (i < n) deg[i] = 0;
}

// ---- fused: W1/W2 -> fp16 panels, x -> fp16, count degrees + edge ranks ----
// The degree count's atomic latency hides under the streaming conversion.
// rank[i] = this edge's arrival position at its destination (atomic return),
// which lets scatter_edges run with NO atomics at all.
__device__ inline void conv_B_elem(const float* B, ushort* Bp, int id) {
    int k  = id >> 6;
    int n4 = (id & 63) * 4;
    float4 v = *(const float4*)(B + (size_t)k * 256 + n4);
    size_t base = (size_t)(k >> 5) * (256 * 32) + (k & 31);
    Bp[base + (size_t)(n4 + 0) * 32] = __half_as_ushort(__float2half(v.x));
    Bp[base + (size_t)(n4 + 1) * 32] = __half_as_ushort(__float2half(v.y));
    Bp[base + (size_t)(n4 + 2) * 32] = __half_as_ushort(__float2half(v.z));
    Bp[base + (size_t)(n4 + 3) * 32] = __half_as_ushort(__float2half(v.w));
}

__global__ void convert_count(const float* __restrict__ W1, ushort* __restrict__ B1p,
                              const float* __restrict__ W2, ushort* __restrict__ B2p,
                              const float* __restrict__ x, ushort* __restrict__ xh,
                              int total4, const int* __restrict__ dst,
                              int* __restrict__ rank, int* __restrict__ deg, int e) {
    int id = blockIdx.x * 256 + threadIdx.x;
    constexpr int C1 = IN_DIM * 64;
    constexpr int C2 = C1 + HID * 64;
    if (id < C1) {
        conv_B_elem(W1, B1p, id);
    } else if (id < C2) {
        conv_B_elem(W2, B2p, id - C1);
    } else if (id < C2 + total4) {
        int i = id - C2;
        float4 v = *(const float4*)(x + (size_t)i * 4);
        ushort4 o;
        o.x = __half_as_ushort(__float2half(v.x));
        o.y = __half_as_ushort(__float2half(v.y));
        o.z = __half_as_ushort(__float2half(v.z));
        o.w = __half_as_ushort(__float2half(v.w));
        *(ushort4*)(xh + (size_t)i * 4) = o;
    } else {
        int i = id - (C2 + total4);
        if (i < e) rank[i] = atomicAdd(&deg[dst[i]], 1);
    }
}

// ---- scan phase 1: per-block scan + block total; also emits dinv ----
__global__ __launch_bounds__(256) void scan_partial(const int* __restrict__ deg,
                                                    int* __restrict__ escan,
                                                    int* __restrict__ blocksum,
                                                    float* __restrict__ dinv, int n) {
    __shared__ int lds[256];
    int t = threadIdx.x;
    int i = blockIdx.x * 256 + t;
    int v = (i < n) ? deg[i] : 0;
    if (i < n) dinv[i] = rsqrtf((float)v + 1.0f);
    lds[t] = v;
    __syncthreads();
    for (int off = 1; off < 256; off <<= 1) {
        int a = lds[t];
        int w = (t >= off) ? lds[t - off] : 0;
        __syncthreads();
        lds[t] = a + w;
        __syncthreads();
    }
    if (i < n) escan[i] = lds[t] - v;
    if (t == 255) blocksum[blockIdx.x] = lds[255];
}

// ---- scan phases 2+3 fused ----
__global__ __launch_bounds__(256) void scan_rest(const int* __restrict__ escan,
                                                 const int* __restrict__ blocksum,
                                                 int nb, int* __restrict__ rowptr, int n) {
    __shared__ int lds[256];
    int t = threadIdx.x;
    int v = (t < nb) ? blocksum[t] : 0;
    lds[t] = v;
    __syncthreads();
    for (int off = 1; off < 256; off <<= 1) {
        int a = lds[t];
        int w = (t >= off) ? lds[t - off] : 0;
        __syncthreads();
        lds[t] = a + w;
        __syncthreads();
    }
    int boff = (blockIdx.x > 0) ? lds[blockIdx.x - 1] : 0;
    int i = blockIdx.x * 256 + t;
    if (i < n) rowptr[i] = escan[i] + boff;
    if (blockIdx.x == 0 && t == 0) rowptr[n] = lds[nb - 1];
}

// Atomic-free scatter: position = rowptr[d] + rank[i] (rank from count pass).
__global__ void scatter_edges(const int* __restrict__ src, const int* __restrict__ dst,
                              const int* __restrict__ rowptr,
                              const int* __restrict__ rank,
                              const float* __restrict__ dinv,
                              int2* __restrict__ esw, int e) {
    int i = blockIdx.x * blockDim.x + threadIdx.x;
    if (i < e) {
        int d = dst[i];
        int s = src[i];
        esw[rowptr[d] + rank[i]] = make_int2(s, __float_as_int(dinv[s] * dinv[d]));
    }
}

// ---------------- aggregation: one wave per node, fp16 gather, 8-deep MLP --
// Edge stream is packed int2 (src, weight) -> one uint2 load per edge.
template <int K>  // K halves per row: 128 or 256
__global__ __launch_bounds__(256) void aggregate_p(const ushort* __restrict__ h,
                                                   const int* __restrict__ rowptr,
                                                   const int2* __restrict__ esw,
                                                   const float* __restrict__ dinv,
                                                   ushort* __restrict__ Pp,
                                                   int n, int Mp) {
    constexpr int VH = K / 64;  // halves per lane: 2 or 4
    int wid  = (blockIdx.x * 256 + threadIdx.x) >> 6;
    int lane = threadIdx.x & 63;
    if (wid >= n) return;
    float di = dinv[wid];
    float sw = di * di;
    float acc[VH];
    {
        const ushort* row = h + (size_t)wid * K + lane * VH;
        if constexpr (VH == 4) {
            uint2 u = *(const uint2*)row;
            float2 fa = __half22float2(*(__half2*)&u.x);
            float2 fb = __half22float2(*(__half2*)&u.y);
            acc[0] = fa.x * sw; acc[1] = fa.y * sw; acc[2] = fb.x * sw; acc[3] = fb.y * sw;
        } else {
            uint u = *(const uint*)row;
            float2 fa = __half22float2(*(__half2*)&u);
            acc[0] = fa.x * sw; acc[1] = fa.y * sw;
        }
    }
    int beg = rowptr[wid], fin = rowptr[wid + 1];
    for (int b = beg; b < fin; b += 64) {
        int cnt = fin - b;
        if (cnt > 64) cnt = 64;
        int2 pk = (lane < cnt) ? esw[b + lane] : make_int2(0, 0);
        int   sv = pk.x;
        float wv = __int_as_float(pk.y);
        int t = 0;
        for (; t + 8 <= cnt; t += 8) {
            float wr[8];
            if constexpr (VH == 4) {
                uint2 u[8];
#pragma unroll
                for (int k = 0; k < 8; k++) {
                    int s = __shfl(sv, t + k);
                    wr[k] = __shfl(wv, t + k);
                    u[k] = *(const uint2*)(h + (size_t)s * K + lane * VH);
                }
#pragma unroll
                for (int k = 0; k < 8; k++) {
                    float2 fa = __half22float2(*(__half2*)&u[k].x);
                    float2 fb = __half22float2(*(__half2*)&u[k].y);
                    acc[0] += fa.x * wr[k]; acc[1] += fa.y * wr[k];
                    acc[2] += fb.x * wr[k]; acc[3] += fb.y * wr[k];
                }
            } else {
                uint u[8];
#pragma unroll
                for (int k = 0; k < 8; k++) {
                    int s = __shfl(sv, t + k);
                    wr[k] = __shfl(wv, t + k);
                    u[k] = *(const uint*)(h + (size_t)s * K + lane * VH);
                }
#pragma unroll
                for (int k = 0; k < 8; k++) {
                    float2 fa = __half22float2(*(__half2*)&u[k]);
                    acc[0] += fa.x * wr[k]; acc[1] += fa.y * wr[k];
                }
            }
        }
        for (; t + 4 <= cnt; t += 4) {
            float wr[4];
            if constexpr (VH == 4) {
                uint2 u[4];
#pragma unroll
                for (int k = 0; k < 4; k++) {
                    int s = __shfl(sv, t + k);
                    wr[k] = __shfl(wv, t + k);
                    u[k] = *(const uint2*)(h + (size_t)s * K + lane * VH);
                }
#pragma unroll
                for (int k = 0; k < 4; k++) {
                    float2 fa = __half22float2(*(__half2*)&u[k].x);
                    float2 fb = __half22float2(*(__half2*)&u[k].y);
                    acc[0] += fa.x * wr[k]; acc[1] += fa.y * wr[k];
                    acc[2] += fb.x * wr[k]; acc[3] += fb.y * wr[k];
                }
            } else {
                uint u[4];
#pragma unroll
                for (int k = 0; k < 4; k++) {
                    int s = __shfl(sv, t + k);
                    wr[k] = __shfl(wv, t + k);
                    u[k] = *(const uint*)(h + (size_t)s * K + lane * VH);
                }
#pragma unroll
                for (int k = 0; k < 4; k++) {
                    float2 fa = __half22float2(*(__half2*)&u[k]);
                    acc[0] += fa.x * wr[k]; acc[1] += fa.y * wr[k];
                }
            }
        }
        for (; t < cnt; t++) {
            int   s = __shfl(sv, t);
            float w = __shfl(wv, t);
            const ushort* r = h + (size_t)s * K + lane * VH;
            if constexpr (VH == 4) {
                uint2 u = *(const uint2*)r;
                float2 fa = __half22float2(*(__half2*)&u.x);
                float2 fb = __half22float2(*(__half2*)&u.y);
                acc[0] += fa.x * w; acc[1] += fa.y * w;
                acc[2] += fb.x * w; acc[3] += fb.y * w;
            } else {
                uint u = *(const uint*)r;
                float2 fa = __half22float2(*(__half2*)&u);
                acc[0] += fa.x * w; acc[1] += fa.y * w;
            }
        }
    }
    int kglob = lane * VH;
    int chunk = kglob >> 5;
    int inner = kglob & 31;
    size_t base = (size_t)chunk * Mp * 32 + (size_t)wid * 32 + inner;
    if constexpr (VH == 4) {
        __half2 p0 = __floats2half2_rn(acc[0], acc[1]);
        __half2 p1 = __floats2half2_rn(acc[2], acc[3]);
        *(uint2*)&Pp[base] = make_uint2(*(uint*)&p0, *(uint*)&p1);
    } else {
        __half2 p0 = __floats2half2_rn(acc[0], acc[1]);
        *(uint*)&Pp[base] = *(uint*)&p0;
    }
}

// ---------------- fp16 MFMA GEMM: A + B both via LDS-DMA (m97-style) -------
// MODE 1: C16[M,256] = fp16(relu(A@B + bias))
// MODE 2: out[M,2]  = relu(A@B + bias) @ Wl + bl
template <int K, int MODE>
__global__ __launch_bounds__(256, 3) void gemm_f16(const ushort* __restrict__ Ap,
                                                   const ushort* __restrict__ Bp,
                                                   const float* __restrict__ bias,
                                                   ushort* __restrict__ C16,
                                                   const float* __restrict__ Wl,
                                                   const float* __restrict__ bl,
                                                   float* __restrict__ out,
                                                   int M, int Mp) {
    constexpr int NC = K / 32;
    __shared__ ushort Asm[NC * 1024];   // A tile [chunk][row 0..31][32]
    __shared__ ushort Bsm[2][8192];     // B chunk dbuf (16 KB each)
    __shared__ float part[4][32][2];    // MODE 2 only

    int tid  = threadIdx.x;
    int w    = tid >> 6;
    int lane = tid & 63;
    int l15  = lane & 15;
    int quad = lane >> 4;
    int row0 = blockIdx.x * 32;

    constexpr int TOTA = NC * 2;
    for (int j = w; j < TOTA; j += 4) {
        int c   = j >> 1;
        int sub = j & 1;
        const ushort* g = Ap + (size_t)c * Mp * 32 + (size_t)(row0 + sub * 16) * 32;
        ushort* l = Asm + c * 1024 + sub * 512;
        __builtin_amdgcn_global_load_lds(
            (const __attribute__((address_space(1))) uint*)(g + (size_t)lane * 8),
            (__attribute__((address_space(3))) uint*)l, 16, 0, 0);
    }
#pragma unroll
    for (int j = 0; j < 4; j++) {
        int seg = w * 4 + j;
        const ushort* g = Bp + (size_t)seg * 512;
        ushort* l = Bsm[0] + seg * 512;
        __builtin_amdgcn_global_load_lds(
            (const __attribute__((address_space(1))) uint*)(g + (size_t)lane * 8),
            (__attribute__((address_space(3))) uint*)l, 16, 0, 0);
    }

    f32x4 acc[2][4] = {};
#pragma unroll
    for (int c = 0; c < NC; c++) {
        __syncthreads();
        if (c + 1 < NC) {
            int nb_ = (c + 1) & 1;
#pragma unroll
            for (int j = 0; j < 4; j++) {
                int seg = w * 4 + j;
                const ushort* g = Bp + (size_t)(c + 1) * 8192 + (size_t)seg * 512;
                ushort* l = Bsm[nb_] + seg * 512;
                __builtin_amdgcn_global_load_lds(
                    (const __attribute__((address_space(1))) uint*)(g + (size_t)lane * 8),
                    (__attribute__((address_space(3))) uint*)l, 16, 0, 0);
            }
        }
        f16x8 fa[2], fb[4];
#pragma unroll
        for (int i = 0; i < 2; i++) {
            int off = c * 1024 + (i * 16 + l15) * 32 + quad * 8;
            fa[i] = *(const f16x8*)&Asm[off];
        }
#pragma unroll
        for (int j = 0; j < 4; j++) {
            int off = (w * 64 + j * 16 + l15) * 32 + quad * 8;
            fb[j] = *(const f16x8*)&Bsm[c & 1][off];
        }
#pragma unroll
        for (int i = 0; i < 2; i++)
#pragma unroll
            for (int j = 0; j < 4; j++)
                acc[i][j] = __builtin_amdgcn_mfma_f32_16x16x32_f16(fa[i], fb[j], acc[i][j], 0, 0, 0);
    }

    float bj[4];
#pragma unroll
    for (int j = 0; j < 4; j++) bj[j] = bias[w * 64 + j * 16 + l15];

    if constexpr (MODE == 1) {
#pragma unroll
        for (int i = 0; i < 2; i++)
#pragma unroll
            for (int reg = 0; reg < 4; reg++) {
                int r = row0 + i * 16 + quad * 4 + reg;
                if (r < M) {
                    ushort* cp = C16 + (size_t)r * 256 + w * 64 + l15;
#pragma unroll
                    for (int j = 0; j < 4; j++) {
                        float v = fmaxf(acc[i][j][reg] + bj[j], 0.f);
                        cp[j * 16] = __half_as_ushort(__float2half(v));
                    }
                }
            }
    } else {
        float wl0[4], wl1[4];
#pragma unroll
        for (int j = 0; j < 4; j++) {
            int cj = w * 64 + j * 16 + l15;
            float2 wv = *(const float2*)(Wl + cj * 2);
            wl0[j] = wv.x; wl1[j] = wv.y;
        }
#pragma unroll
        for (int i = 0; i < 2; i++)
#pragma unroll
            for (int reg = 0; reg < 4; reg++) {
                float s0 = 0.f, s1 = 0.f;
#pragma unroll
                for (int j = 0; j < 4; j++) {
                    float v = fmaxf(acc[i][j][reg] + bj[j], 0.f);
                    s0 += v * wl0[j];
                    s1 += v * wl1[j];
                }
#pragma unroll
                for (int off = 1; off < 16; off <<= 1) {
                    s0 += __shfl_xor(s0, off);
                    s1 += __shfl_xor(s1, off);
                }
                if (l15 == 0) {
                    int r = i * 16 + quad * 4 + reg;
                    part[w][r][0] = s0;
                    part[w][r][1] = s1;
                }
            }
        __syncthreads();
        if (tid < 64) {
            int r = tid >> 1, o = tid & 1;
            int grr = row0 + r;
            if (grr < M) {
                float s = part[0][r][o] + part[1][r][o] + part[2][r][o] + part[3][r][o] + bl[o];
                out[(size_t)grr * 2 + o] = s;
            }
        }
    }
}

// ---------------- launch ----------------

extern "C" void kernel_launch(void* const* d_in, const int* in_sizes, int n_in,
                              void* d_out, int out_size, void* d_ws, size_t ws_size,
                              hipStream_t stream) {
    const float* x  = (const float*)d_in[0];
    const int*   ei = (const int*)d_in[1];
    const float* W1 = (const float*)d_in[2];
    const float* b1 = (const float*)d_in[3];
    const float* W2 = (const float*)d_in[4];
    const float* b2 = (const float*)d_in[5];
    const float* Wl = (const float*)d_in[6];
    const float* bl = (const float*)d_in[7];
    float* out = (float*)d_out;

    int n = in_sizes[0] / IN_DIM;  // 50000
    int e = in_sizes[1] / 2;       // 600000
    const int* src = ei;
    const int* dst = ei + e;

    int gblocks = (n + 31) / 32;   // BM=32
    int Mp = gblocks * 32;

    char* ws = (char*)d_ws;
    size_t off = 0;
    auto alloc = [&](size_t bytes) -> void* {
        void* p = ws + off;
        off += (bytes + 255) & ~(size_t)255;
        return p;
    };
    int*    deg    = (int*)alloc((size_t)n * 4);
    float*  dinv   = (float*)alloc((size_t)n * 4);
    int*    rowptr = (int*)alloc((size_t)(n + 1) * 4);
    int*    escan  = (int*)alloc((size_t)n * 4);
    int*    bsum   = (int*)alloc(256 * 4);
    int*    rank   = (int*)alloc((size_t)e * 4);
    int2*   esw    = (int2*)alloc((size_t)e * 8);
    ushort* xh     = (ushort*)alloc((size_t)n * IN_DIM * 2);
    ushort* h1     = (ushort*)alloc((size_t)n * HID * 2);
    ushort* A1p    = (ushort*)alloc((size_t)Mp * IN_DIM * 2);
    ushort* A2p    = (ushort*)alloc((size_t)Mp * HID * 2);
    ushort* B1p    = (ushort*)alloc((size_t)IN_DIM * 256 * 2);
    ushort* B2p    = (ushort*)alloc((size_t)HID * 256 * 2);

    int nb = (n + 255) / 256;   // 196 (<= 256 required by scan_rest)
    int eb = (e + 255) / 256;

    zero_deg<<<nb, 256, 0, stream>>>(deg, n);

    int total4 = n * IN_DIM / 4;
    int citems = IN_DIM * 64 + HID * 64 + total4 + e;
    convert_count<<<(citems + 255) / 256, 256, 0, stream>>>(W1, B1p, W2, B2p, x, xh,
                                                            total4, dst, rank, deg, e);

    scan_partial<<<nb, 256, 0, stream>>>(deg, escan, bsum, dinv, n);
    scan_rest<<<nb, 256, 0, stream>>>(escan, bsum, nb, rowptr, n);
    scatter_edges<<<eb, 256, 0, stream>>>(src, dst, rowptr, rank, dinv, esw, e);

    // layer 1: aggregate fp16 x -> A1 panel, DMA-dbuf fp16-MFMA GEMM -> fp16 h1
    aggregate_p<IN_DIM><<<(n + 3) / 4, 256, 0, stream>>>(xh, rowptr, esw, dinv,
                                                         A1p, n, Mp);
    gemm_f16<IN_DIM, 1><<<gblocks, 256, 0, stream>>>(A1p, B1p, b1, h1,
                                                     nullptr, nullptr, nullptr, n, Mp);

    // layer 2: aggregate fp16 h1 -> A2 panel, DMA-dbuf GEMM + final projection
    aggregate_p<HID><<<(n + 3) / 4, 256, 0, stream>>>(h1, rowptr, esw, dinv,
                                                      A2p, n, Mp);
    gemm_f16<HID, 2><<<gblocks, 256, 0, stream>>>(A2p, B2p, b2, nullptr,
                                                  Wl, bl, out, n, Mp);
}